// Round 3
// baseline (271.538 us; speedup 1.0000x reference)
//
#include <hip/hip_runtime.h>
#include <hip/hip_bf16.h>

#define EMBED 1024
#define VEC   (EMBED / 4)   // 256 float4 per row
#define TPB   8             // tokens per block

// 8 tokens per block, 256 threads. All 8 token-ids are wave-uniform scalar
// loads hoisted up front; then 8 independent float4 row-loads per thread are
// issued back-to-back (128 B in flight/thread) before the stores. Row reads
// and output writes are fully coalesced 4 KB streams.
__global__ __launch_bounds__(256) void Embedding_19937238188585_kernel(
    const int* __restrict__ ids,
    const float4* __restrict__ w,
    float4* __restrict__ out)
{
    const int base = blockIdx.x * TPB;
    const int t    = threadIdx.x;

    int id[TPB];
#pragma unroll
    for (int k = 0; k < TPB; ++k) id[k] = ids[base + k];   // uniform -> s_load

    float4 v[TPB];
#pragma unroll
    for (int k = 0; k < TPB; ++k)
        v[k] = w[(size_t)id[k] * VEC + t];                 // 8 loads in flight

    float4* __restrict__ dst = out + (size_t)base * VEC + t;
#pragma unroll
    for (int k = 0; k < TPB; ++k)
        dst[(size_t)k * VEC] = v[k];
}

extern "C" void kernel_launch(void* const* d_in, const int* in_sizes, int n_in,
                              void* d_out, int out_size, void* d_ws, size_t ws_size,
                              hipStream_t stream) {
    const int*    ids = (const int*)d_in[0];      // token_ids, int32, [16384]
    const float4* w   = (const float4*)d_in[1];   // weights, fp32, [50257, 1024]
    float4*       out = (float4*)d_out;           // fp32, [4, 4096, 1024]

    const int n_tokens = in_sizes[0];             // 16384
    Embedding_19937238188585_kernel<<<n_tokens / TPB, 256, 0, stream>>>(ids, w, out);
}